// Round 7
// baseline (350.988 us; speedup 1.0000x reference)
//
#include <hip/hip_runtime.h>
#include <math.h>

#define D 128

// ---------------------------------------------------------------------------
// Collapsed linear GCN (math unchanged, absmax 0.0 since R0):
//   u0 = 1/N,  u_{k+1}[s] = sum_{e: src_e=s} inv_deg[dst_e] * u_k[dst_e]
//   mean(h3) = r@W0W1W2 + s2*(b0@W1W2) + s1*(b1@W2) + b2,  r = u3^T feat
// R2-R5: LDS histograms, ILP, split-K final.
// R6: bucket edges by src-quarter ONCE (reused by 3 prop scans -> no 4x
// rescan, no hit-test waste); reduces 64-thread blocks (391 blocks, all CUs);
// fpart parallel pre-reduce so final_kernel isn't latency-serial on 786 KB.
// ---------------------------------------------------------------------------

// deg pass (unbucketed): rep[g][h][b][HN] += 1 for dst in quarter
__global__ __launch_bounds__(256) void scan_deg(
        const int* __restrict__ dst_p, const int* __restrict__ dst_s,
        float* __restrict__ rep, int E, int N, int HN, int B, int H) {
    const int b = blockIdx.x, h = blockIdx.y, g = blockIdx.z;
    const int* tgt = g ? dst_s : dst_p;

    extern __shared__ float lds[];
    {
        float4 z = make_float4(0.f, 0.f, 0.f, 0.f);
        float4* l4 = (float4*)lds;
        for (int i = threadIdx.x; i < HN / 4; i += blockDim.x) l4[i] = z;
    }
    __syncthreads();

    const int lo = h * HN;
    const int hi = min(lo + HN, N);
    const unsigned span = (unsigned)(hi - lo);
    int C = (E + B - 1) / B;
    C = (C + 15) & ~15;
    const int e0 = b * C;
    const int e1 = min(e0 + C, E);

    for (int e = e0 + (int)threadIdx.x * 16; e < e1; e += blockDim.x * 16) {
        if (e + 16 <= e1) {
            int idx[16];
            #pragma unroll
            for (int q = 0; q < 4; ++q) {
                int4 t4 = *(const int4*)(tgt + e + 4 * q);
                idx[4 * q + 0] = t4.x; idx[4 * q + 1] = t4.y;
                idx[4 * q + 2] = t4.z; idx[4 * q + 3] = t4.w;
            }
            #pragma unroll
            for (int k = 0; k < 16; ++k)
                if ((unsigned)(idx[k] - lo) < span) atomicAdd(&lds[idx[k] - lo], 1.0f);
        } else {
            for (int e2 = e; e2 < e1; ++e2) {
                int t = tgt[e2];
                if ((unsigned)(t - lo) < span) atomicAdd(&lds[t - lo], 1.0f);
            }
        }
    }
    __syncthreads();

    float* dst = rep + (((size_t)g * H + h) * B + b) * HN;
    float4* d4 = (float4*)dst;
    const float4* l4 = (const float4*)lds;
    for (int i = threadIdx.x; i < HN / 4; i += blockDim.x) d4[i] = l4[i];
}

// count edges per src-quarter per chunk; also zero sums (runs first)
__global__ __launch_bounds__(256) void bucket_count(
        const int* __restrict__ src_p, const int* __restrict__ src_s,
        int* __restrict__ cnt, float* __restrict__ sums, int E, int HN, int B0) {
    const int b = blockIdx.x, g = blockIdx.y;
    const int* src = g ? src_s : src_p;
    __shared__ int c[4];
    if (threadIdx.x < 4) c[threadIdx.x] = 0;
    if (b == 0 && g == 0 && threadIdx.x < 16) sums[threadIdx.x] = 0.f;
    __syncthreads();
    int C = (E + B0 - 1) / B0; C = (C + 7) & ~7;
    const int e0 = b * C, e1 = min(e0 + C, E);
    const int hh = HN, h2 = 2 * HN, h3 = 3 * HN;
    int lc0 = 0, lc1 = 0, lc2 = 0, lc3 = 0;
    for (int e = e0 + (int)threadIdx.x * 8; e < e1; e += 2048) {
        if (e + 8 <= e1) {
            int4 a = *(const int4*)(src + e);
            int4 bb = *(const int4*)(src + e + 4);
            int v[8] = {a.x, a.y, a.z, a.w, bb.x, bb.y, bb.z, bb.w};
            #pragma unroll
            for (int k = 0; k < 8; ++k) {
                int h = (v[k] >= h2) ? (v[k] >= h3 ? 3 : 2) : (v[k] >= hh ? 1 : 0);
                lc0 += (h == 0); lc1 += (h == 1); lc2 += (h == 2); lc3 += (h == 3);
            }
        } else {
            for (int e2 = e; e2 < e1; ++e2) {
                int v = src[e2];
                int h = (v >= h2) ? (v >= h3 ? 3 : 2) : (v >= hh ? 1 : 0);
                lc0 += (h == 0); lc1 += (h == 1); lc2 += (h == 2); lc3 += (h == 3);
            }
        }
    }
    atomicAdd(&c[0], lc0); atomicAdd(&c[1], lc1);
    atomicAdd(&c[2], lc2); atomicAdd(&c[3], lc3);
    __syncthreads();
    if (threadIdx.x < 4) cnt[((size_t)g * B0 + b) * 4 + threadIdx.x] = c[threadIdx.x];
}

// parallel prefix over cnt[g][b][h] -> base[g][b][h] (global pair index),
// meta[0..7]=startGH, meta[8..15]=cntGH. Requires B0==256, 256 threads.
__global__ __launch_bounds__(256) void bucket_prefix(
        const int* __restrict__ cnt, int* __restrict__ base, int* __restrict__ meta,
        int B0, int capg) {
    __shared__ int sb[256];
    __shared__ int tot[8], st[8];
    const int tid = threadIdx.x;
    for (int gh = 0; gh < 8; ++gh) {
        int g = gh >> 2, h = gh & 3;
        int v = cnt[((size_t)g * B0 + tid) * 4 + h];
        sb[tid] = v;
        __syncthreads();
        for (int off = 1; off < 256; off <<= 1) {
            int t = (tid >= off) ? sb[tid - off] : 0;
            __syncthreads();
            sb[tid] += t;
            __syncthreads();
        }
        base[((size_t)g * B0 + tid) * 4 + h] = sb[tid] - v;  // exclusive, local
        if (tid == 255) tot[gh] = sb[255];
        __syncthreads();
    }
    if (tid == 0) {
        for (int g = 0; g < 2; ++g) {
            int off = 0;
            for (int h = 0; h < 4; ++h) {
                int s = (off + 3) & ~3;
                st[g * 4 + h] = s + g * capg;
                off = s + tot[g * 4 + h];
            }
        }
    }
    __syncthreads();
    for (int gh = 0; gh < 8; ++gh) {
        int g = gh >> 2, h = gh & 3;
        base[((size_t)g * B0 + tid) * 4 + h] += st[gh];
    }
    if (tid < 8) { meta[tid] = st[tid]; meta[8 + tid] = tot[tid]; }
}

// scatter (src,dst) pairs into quarter buckets using LDS cursors
__global__ __launch_bounds__(256) void bucket_scatter(
        const int* __restrict__ src_p, const int* __restrict__ dst_p,
        const int* __restrict__ src_s, const int* __restrict__ dst_s,
        const int* __restrict__ base, int2* __restrict__ pairs,
        int E, int HN, int B0) {
    const int b = blockIdx.x, g = blockIdx.y;
    const int* src = g ? src_s : src_p;
    const int* dst = g ? dst_s : dst_p;
    __shared__ int cur[4];
    if (threadIdx.x < 4) cur[threadIdx.x] = base[((size_t)g * B0 + b) * 4 + threadIdx.x];
    __syncthreads();
    int C = (E + B0 - 1) / B0; C = (C + 7) & ~7;
    const int e0 = b * C, e1 = min(e0 + C, E);
    const int hh = HN, h2 = 2 * HN, h3 = 3 * HN;
    for (int e = e0 + (int)threadIdx.x * 8; e < e1; e += 2048) {
        if (e + 8 <= e1) {
            int4 sa = *(const int4*)(src + e), sb2 = *(const int4*)(src + e + 4);
            int4 da = *(const int4*)(dst + e), db2 = *(const int4*)(dst + e + 4);
            int sv[8] = {sa.x, sa.y, sa.z, sa.w, sb2.x, sb2.y, sb2.z, sb2.w};
            int dv[8] = {da.x, da.y, da.z, da.w, db2.x, db2.y, db2.z, db2.w};
            #pragma unroll
            for (int k = 0; k < 8; ++k) {
                int h = (sv[k] >= h2) ? (sv[k] >= h3 ? 3 : 2) : (sv[k] >= hh ? 1 : 0);
                int pos = atomicAdd(&cur[h], 1);
                pairs[pos] = make_int2(sv[k], dv[k]);
            }
        } else {
            for (int e2 = e; e2 < e1; ++e2) {
                int sv = src[e2], dv = dst[e2];
                int h = (sv >= h2) ? (sv >= h3 ? 3 : 2) : (sv >= hh ? 1 : 0);
                int pos = atomicAdd(&cur[h], 1);
                pairs[pos] = make_int2(sv, dv);
            }
        }
    }
}

// bucketed prop pass: lds[src-lo] += w[g*N+dst]*scale over this (g,h) slice
__global__ __launch_bounds__(256) void scan_bucket(
        const int2* __restrict__ pairs, const int* __restrict__ meta,
        const float* __restrict__ w, float* __restrict__ rep,
        int N, int HN, int B2, float scale) {
    const int b = blockIdx.x, h = blockIdx.y, g = blockIdx.z;
    const int start = meta[g * 4 + h];
    const int cntgh = meta[8 + g * 4 + h];
    const float* wg = w + (size_t)g * N;

    extern __shared__ float lds[];
    {
        float4 z = make_float4(0.f, 0.f, 0.f, 0.f);
        float4* l4 = (float4*)lds;
        for (int i = threadIdx.x; i < HN / 4; i += blockDim.x) l4[i] = z;
    }
    __syncthreads();

    const int lo = h * HN;
    int C = (cntgh + B2 - 1) / B2; C = (C + 15) & ~15;
    const int p0 = start + b * C;
    const int pend = start + cntgh;
    const int p1 = min(p0 + C, pend);

    for (int p = p0 + (int)threadIdx.x * 16; p < p1; p += 4096) {
        if (p + 16 <= p1) {
            const int4* q = (const int4*)(pairs + p);  // p % 4 == 0 -> 32B aligned
            int4 qq[8];
            #pragma unroll
            for (int i = 0; i < 8; ++i) qq[i] = q[i];
            int s[16], d[16];
            #pragma unroll
            for (int k = 0; k < 8; ++k) {
                s[2 * k] = qq[k].x; d[2 * k] = qq[k].y;
                s[2 * k + 1] = qq[k].z; d[2 * k + 1] = qq[k].w;
            }
            float v[16];
            #pragma unroll
            for (int k = 0; k < 16; ++k) v[k] = wg[d[k]];
            #pragma unroll
            for (int k = 0; k < 16; ++k) atomicAdd(&lds[s[k] - lo], v[k] * scale);
        } else {
            for (int p2 = p; p2 < p1; ++p2) {
                int2 pr = pairs[p2];
                atomicAdd(&lds[pr.x - lo], wg[pr.y] * scale);
            }
        }
    }
    __syncthreads();

    float* dstp = rep + (((size_t)g * 4 + h) * B2 + b) * HN;
    float4* d4 = (float4*)dstp;
    const float4* l4 = (const float4*)lds;
    for (int i = threadIdx.x; i < HN / 4; i += blockDim.x) d4[i] = l4[i];
}

// inv[i] = 1 / max(sum_b rep[...], 1), float4/thread, 64-thread blocks
__global__ __launch_bounds__(64) void reduce_inv(
        const float* __restrict__ rep, float* __restrict__ inv,
        int N, int HN, int H, int B) {
    int i = (blockIdx.x * 64 + threadIdx.x) * 4;
    if (i >= 2 * N) return;
    int g = (i < N) ? 0 : 1;
    int n = i - g * N;
    int h = n / HN, l = n - h * HN;
    const float* base = rep + (((size_t)g * H + h) * B) * HN + l;
    float4 s = make_float4(0.f, 0.f, 0.f, 0.f);
    #pragma unroll 16
    for (int b = 0; b < B; b++) {
        float4 v = *(const float4*)(base + (size_t)b * HN);
        s.x += v.x; s.y += v.y; s.z += v.z; s.w += v.w;
    }
    float4 r;
    r.x = 1.0f / fmaxf(s.x, 1.0f); r.y = 1.0f / fmaxf(s.y, 1.0f);
    r.z = 1.0f / fmaxf(s.z, 1.0f); r.w = 1.0f / fmaxf(s.w, 1.0f);
    *(float4*)(inv + i) = r;
}

// u = sum_b rep; optional out_u, out_w = u*inv; optional per-graph sums
__global__ __launch_bounds__(64) void reduce_u(
        const float* __restrict__ rep, const float* __restrict__ inv,
        float* __restrict__ out_u, float* __restrict__ out_w,
        float* __restrict__ sums, int s_idx, int N, int HN, int H, int B) {
    int i = (blockIdx.x * 64 + threadIdx.x) * 4;
    float tp = 0.f, ts = 0.f;
    if (i < 2 * N) {
        int g = (i < N) ? 0 : 1;
        int n = i - g * N;
        int h = n / HN, l = n - h * HN;
        const float* base = rep + (((size_t)g * H + h) * B) * HN + l;
        float4 u = make_float4(0.f, 0.f, 0.f, 0.f);
        #pragma unroll 16
        for (int b = 0; b < B; b++) {
            float4 v = *(const float4*)(base + (size_t)b * HN);
            u.x += v.x; u.y += v.y; u.z += v.z; u.w += v.w;
        }
        if (out_u) *(float4*)(out_u + i) = u;
        if (out_w) {
            float4 iv = *(const float4*)(inv + i);
            *(float4*)(out_w + i) = make_float4(u.x * iv.x, u.y * iv.y, u.z * iv.z, u.w * iv.w);
        }
        float t = u.x + u.y + u.z + u.w;
        if (g == 0) tp = t; else ts = t;
    }
    if (sums) {
        __shared__ float sm0[64], sm1[64];
        sm0[threadIdx.x] = tp; sm1[threadIdx.x] = ts;
        __syncthreads();
        for (int s = 32; s > 0; s >>= 1) {
            if ((int)threadIdx.x < s) {
                sm0[threadIdx.x] += sm0[threadIdx.x + s];
                sm1[threadIdx.x] += sm1[threadIdx.x + s];
            }
            __syncthreads();
        }
        if (threadIdx.x == 0) {
            if (sm0[0] != 0.f) atomicAdd(&sums[0 * 2 + s_idx], sm0[0]);
            if (sm1[0] != 0.f) atomicAdd(&sums[1 * 2 + s_idx], sm1[0]);
        }
    }
}

// fpart[(g*NB+blk)][c] = partial of u3^T feat over this block's rows
__global__ __launch_bounds__(256) void featsum_kernel(
        const float* __restrict__ feat_p, const float* __restrict__ feat_s,
        const float* __restrict__ u3, float* __restrict__ fpart, int N) {
    const int g = blockIdx.y;
    const float* feat = g ? feat_s : feat_p;
    const float* u = u3 + (size_t)g * N;
    const int nb = gridDim.x;
    const int col4 = threadIdx.x & 31;
    const int rgrp = threadIdx.x >> 5;
    const int rows_per_block = (N + nb - 1) / nb;
    const int r0 = blockIdx.x * rows_per_block;
    const int r1 = min(r0 + rows_per_block, N);

    const float4* f4 = (const float4*)feat;
    float4 acc = make_float4(0.f, 0.f, 0.f, 0.f);
    int n = r0 + rgrp;
    for (; n + 24 < r1; n += 32) {
        float w0 = u[n], w1 = u[n + 8], w2 = u[n + 16], w3 = u[n + 24];
        float4 v0 = f4[(size_t)n * 32 + col4];
        float4 v1 = f4[(size_t)(n + 8) * 32 + col4];
        float4 v2 = f4[(size_t)(n + 16) * 32 + col4];
        float4 v3 = f4[(size_t)(n + 24) * 32 + col4];
        acc.x += w0 * v0.x + w1 * v1.x + w2 * v2.x + w3 * v3.x;
        acc.y += w0 * v0.y + w1 * v1.y + w2 * v2.y + w3 * v3.y;
        acc.z += w0 * v0.z + w1 * v1.z + w2 * v2.z + w3 * v3.z;
        acc.w += w0 * v0.w + w1 * v1.w + w2 * v2.w + w3 * v3.w;
    }
    for (; n < r1; n += 8) {
        float wv = u[n];
        float4 v = f4[(size_t)n * 32 + col4];
        acc.x += wv * v.x; acc.y += wv * v.y; acc.z += wv * v.z; acc.w += wv * v.w;
    }
    __shared__ float4 smem[256];
    smem[threadIdx.x] = acc;
    __syncthreads();
    if (rgrp == 0) {
        float4 t = smem[col4];
        #pragma unroll
        for (int k = 1; k < 8; k++) {
            float4 o = smem[k * 32 + col4];
            t.x += o.x; t.y += o.y; t.z += o.z; t.w += o.w;
        }
        float4* dst = (float4*)(fpart + ((size_t)g * nb + blockIdx.x) * 128);
        dst[col4] = t;
    }
}

// parallel pre-reduce: fpart[2][768][128] -> fpart2[2][16][128] (NB==768)
__global__ __launch_bounds__(256) void fpart_reduce(
        const float* __restrict__ fpart, float* __restrict__ fpart2, int NB) {
    const int b = blockIdx.x, g = blockIdx.y;   // (16, 2)
    const int j = threadIdx.x & 127, half = threadIdx.x >> 7;
    const int per = NB / 16;                    // 48
    const float* fp = fpart + ((size_t)(g * NB + b * per + half * (per / 2))) * 128 + j;
    float s = 0.f;
    #pragma unroll
    for (int k = 0; k < 24; ++k) s += fp[(size_t)k * 128];
    __shared__ float sm[2][128];
    sm[half][j] = s;
    __syncthreads();
    if (half == 0) fpart2[((size_t)g * 16 + b) * 128 + j] = sm[0][j] + sm[1][j];
}

// 512 threads: split-K matvecs. j = tid&127, h = tid>>7.
__global__ __launch_bounds__(512) void final_kernel(
        const float* __restrict__ fpart2,
        const float* __restrict__ sums,
        const float* __restrict__ W0, const float* __restrict__ b0,
        const float* __restrict__ W1, const float* __restrict__ b1,
        const float* __restrict__ W2, const float* __restrict__ b2,
        const float* __restrict__ Wr, const float* __restrict__ br,
        const float* __restrict__ Wm1, const float* __restrict__ bm1,
        const float* __restrict__ Wm2, const float* __restrict__ bm2,
        float* __restrict__ out) {
    __shared__ float x[128];
    __shared__ float part[4][128];
    __shared__ float rvec[256];
    __shared__ float Avec[128], Bvec[128];
    __shared__ float gv[256];
    const int tid = threadIdx.x;
    const int j = tid & 127;
    const int h = tid >> 7;

    auto mv128 = [&](const float* __restrict__ W, float* __restrict__ buf) {
        float p = 0.f;
        const float* Wp = W + (size_t)(h * 32) * 128 + j;
        #pragma unroll
        for (int i = 0; i < 32; ++i) p += buf[h * 32 + i] * Wp[(size_t)i * 128];
        part[h][j] = p;
        __syncthreads();
        if (h == 0) buf[j] = part[0][j] + part[1][j] + part[2][j] + part[3][j];
        __syncthreads();
    };

    // 1. fpart2 reduce -> rvec
    if (tid < 256) {
        int g = tid >> 7;
        const float* fp = fpart2 + (size_t)g * 2048 + (tid & 127);
        float rv = 0.f;
        #pragma unroll
        for (int b = 0; b < 16; ++b) rv += fp[(size_t)b * 128];
        rvec[tid] = rv;
    }
    __syncthreads();

    // 2. bias chains: Avec = b0@W1@W2 (coeff s2), Bvec = b1@W2 (coeff s1)
    if (tid < 128) x[tid] = b0[tid];
    __syncthreads();
    mv128(W1, x);
    mv128(W2, x);
    if (tid < 128) Avec[tid] = x[tid];
    __syncthreads();
    if (tid < 128) x[tid] = b1[tid];
    __syncthreads();
    mv128(W2, x);
    if (tid < 128) Bvec[tid] = x[tid];
    __syncthreads();

    // 3. per-graph chain + readout sigmoid
    for (int g = 0; g < 2; ++g) {
        const float s1 = sums[g * 2 + 0];
        const float s2 = sums[g * 2 + 1];
        if (tid < 128) x[tid] = rvec[g * 128 + tid];
        __syncthreads();
        mv128(W0, x);
        mv128(W1, x);
        mv128(W2, x);
        if (tid < 128) x[tid] += s2 * Avec[tid] + s1 * Bvec[tid] + b2[tid];
        __syncthreads();
        mv128(Wr, x);
        if (tid < 128) gv[g * 128 + tid] = 1.0f / (1.0f + expf(-(x[tid] + br[tid])));
        __syncthreads();
    }

    // 4. match MLP
    {
        float p = 0.f;
        const float* Wp = Wm1 + (size_t)(h * 64) * 128 + j;
        #pragma unroll
        for (int i = 0; i < 64; ++i) p += gv[h * 64 + i] * Wp[(size_t)i * 128];
        part[h][j] = p;
        __syncthreads();
        if (h == 0)
            part[0][j] = (part[0][j] + part[1][j] + part[2][j] + part[3][j] + bm1[j]) * Wm2[j];
        __syncthreads();
        if (tid < 64) part[0][tid] += part[0][tid + 64];
        __syncthreads();
        if (tid < 32) part[0][tid] += part[0][tid + 32];
        __syncthreads();
        if (tid < 16) part[0][tid] += part[0][tid + 16];
        __syncthreads();
        if (tid < 8) part[0][tid] += part[0][tid + 8];
        __syncthreads();
        if (tid < 4) part[0][tid] += part[0][tid + 4];
        __syncthreads();
        if (tid < 2) part[0][tid] += part[0][tid + 2];
        __syncthreads();
        if (tid == 0) out[0] = 1.0f / (1.0f + expf(-(part[0][0] + part[0][1] + bm2[0])));
    }
}

extern "C" void kernel_launch(void* const* d_in, const int* in_sizes, int n_in,
                              void* d_out, int out_size, void* d_ws, size_t ws_size,
                              hipStream_t stream) {
    const float* feat_p = (const float*)d_in[0];
    const int*   src_p  = (const int*)d_in[1];
    const int*   dst_p  = (const int*)d_in[2];
    const float* feat_s = (const float*)d_in[3];
    const int*   src_s  = (const int*)d_in[4];
    const int*   dst_s  = (const int*)d_in[5];
    const float* W0 = (const float*)d_in[6];
    const float* b0 = (const float*)d_in[7];
    const float* W1 = (const float*)d_in[8];
    const float* b1 = (const float*)d_in[9];
    const float* W2 = (const float*)d_in[10];
    const float* b2 = (const float*)d_in[11];
    const float* Wr = (const float*)d_in[12];
    const float* br = (const float*)d_in[13];
    const float* Wm1 = (const float*)d_in[14];
    const float* bm1 = (const float*)d_in[15];
    const float* Wm2 = (const float*)d_in[16];
    const float* bm2 = (const float*)d_in[17];
    float* out = (float*)d_out;

    const int N = in_sizes[0] / D;   // 50000
    const int E = in_sizes[1];       // 1600000
    const int N2 = 2 * N;

    const int H = 4;
    int HN = (N + H - 1) / H;
    HN = (HN + 3) & ~3;              // 12500
    const int NB = 768;
    const int B0 = 256;              // bucket chunks per graph
    const int capg = E + 96;         // pair capacity per graph (alignment slop)

    // ws layout (floats unless noted):
    // sums[16] | inv[2N] | w1[2N] | w2[2N] | u3[2N] | fpart[2*NB*128] |
    // fpart2[2*16*128] | cnt[2*B0*4 ints] | base[2*B0*4 ints] | meta[16 ints] |
    // pairs[2*capg int2] | rep[2*H*B*HN]
    float* ws     = (float*)d_ws;
    float* sums   = ws;
    float* inv    = ws + 16;
    float* w1     = inv + N2;
    float* w2     = w1 + N2;
    float* u3     = w2 + N2;
    float* fpart  = u3 + N2;
    float* fpart2 = fpart + (size_t)2 * NB * 128;
    int*   cnt    = (int*)(fpart2 + 2 * 16 * 128);
    int*   base   = cnt + (size_t)2 * B0 * 4;
    int*   meta   = base + (size_t)2 * B0 * 4;
    // align pairs to 16 B (meta end is 16-int aligned already; enforce anyway)
    size_t off_f  = (size_t)((float*)(meta + 16) - ws);
    off_f = (off_f + 3) & ~(size_t)3;
    int2*  pairs  = (int2*)(ws + off_f);
    float* rep    = ws + off_f + (size_t)2 * capg * 2;

    const size_t head = off_f + (size_t)2 * capg * 2;
    size_t avail = ws_size / sizeof(float);
    int B = 8;
    if (avail > head) {
        size_t bmax = (avail - head) / ((size_t)2 * H * HN);
        if (bmax > 96) bmax = 96;
        B = (int)(bmax & ~(size_t)7);
        if (B < 8) B = 8;
    }

    const int BT = 256;
    const dim3 sgrid(B, H, 2);
    const size_t lds_bytes = (size_t)HN * sizeof(float);
    const int gQ = (N2 / 4 + 63) / 64;
    const float u0 = 1.0f / (float)N;

    // bucket build (also zeroes sums)
    bucket_count<<<dim3(B0, 2), BT, 0, stream>>>(src_p, src_s, cnt, sums, E, HN, B0);
    bucket_prefix<<<1, 256, 0, stream>>>(cnt, base, meta, B0, capg);
    bucket_scatter<<<dim3(B0, 2), BT, 0, stream>>>(src_p, dst_p, src_s, dst_s,
                                                   base, pairs, E, HN, B0);

    // degree (unbucketed dst scan)
    scan_deg<<<sgrid, BT, lds_bytes, stream>>>(dst_p, dst_s, rep, E, N, HN, B, H);
    reduce_inv<<<gQ, 64, 0, stream>>>(rep, inv, N, HN, H, B);

    // prop1..3 on bucketed pairs
    scan_bucket<<<sgrid, BT, lds_bytes, stream>>>(pairs, meta, inv, rep, N, HN, B, u0);
    reduce_u<<<gQ, 64, 0, stream>>>(rep, inv, nullptr, w1, sums, 0, N, HN, H, B);

    scan_bucket<<<sgrid, BT, lds_bytes, stream>>>(pairs, meta, w1, rep, N, HN, B, 1.0f);
    reduce_u<<<gQ, 64, 0, stream>>>(rep, inv, nullptr, w2, sums, 1, N, HN, H, B);

    scan_bucket<<<sgrid, BT, lds_bytes, stream>>>(pairs, meta, w2, rep, N, HN, B, 1.0f);
    reduce_u<<<gQ, 64, 0, stream>>>(rep, inv, u3, nullptr, nullptr, 0, N, HN, H, B);

    featsum_kernel<<<dim3(NB, 2), BT, 0, stream>>>(feat_p, feat_s, u3, fpart, N);
    fpart_reduce<<<dim3(16, 2), BT, 0, stream>>>(fpart, fpart2, NB);

    final_kernel<<<1, 512, 0, stream>>>(fpart2, sums, W0, b0, W1, b1, W2, b2,
                                        Wr, br, Wm1, bm1, Wm2, bm2, out);
}

// Round 8
// 303.403 us; speedup vs baseline: 1.1568x; 1.1568x over previous
//
#include <hip/hip_runtime.h>
#include <math.h>

#define D 128

// ---------------------------------------------------------------------------
// Collapsed linear GCN (math unchanged, absmax 0.0 since R0):
//   u0 = 1/N,  u_{k+1}[s] = sum_{e: src_e=s} inv_deg[dst_e] * u_k[dst_e]
//   mean(h3) = r@W0W1W2 + s2*(b0@W1W2) + s1*(b1@W2) + b2,  r = u3^T feat
// R2-R5: LDS histograms, 16-wide ILP, split-K final.
// R6 FAILED: bucketing cost > hit-test waste (scans are gather-latency-bound,
// L3 absorbs the H=4 re-reads: scan FETCH ~14MB). Reverted.
// R7: scan blocks 512 threads (24 waves/CU, 2x latency hiding; LDS 50KB x3
// still resident); 64-thread reduces; fpart pre-reduce + slim final.
// ---------------------------------------------------------------------------

// scatter pass: rep[g][h][b][HN] partial sums.
//   deg pass:  tgt = dst arrays, w = null  -> +1 per edge
//   prop pass: tgt = src arrays, oth = dst, w -> + w[g*N + dst[e]] * scale
__global__ __launch_bounds__(512) void scan_scatter(
        const int* __restrict__ tgt_p, const int* __restrict__ oth_p,
        const int* __restrict__ tgt_s, const int* __restrict__ oth_s,
        const float* __restrict__ w, float* __restrict__ rep,
        int E, int N, int HN, int B, int H, float scale) {
    const int b = blockIdx.x, h = blockIdx.y, g = blockIdx.z;
    const int* tgt = g ? tgt_s : tgt_p;
    const int* oth = g ? oth_s : oth_p;
    const float* wg = w ? (w + (size_t)g * N) : nullptr;

    extern __shared__ float lds[];  // HN floats (HN % 4 == 0)
    {
        float4 z = make_float4(0.f, 0.f, 0.f, 0.f);
        float4* l4 = (float4*)lds;
        for (int i = threadIdx.x; i < HN / 4; i += blockDim.x) l4[i] = z;
    }
    __syncthreads();

    const int lo = h * HN;
    const int hi = min(lo + HN, N);
    const unsigned span = (unsigned)(hi - lo);
    int C = (E + B - 1) / B;
    C = (C + 15) & ~15;
    const int e0 = b * C;
    const int e1 = min(e0 + C, E);

    for (int e = e0 + (int)threadIdx.x * 16; e < e1; e += (int)blockDim.x * 16) {
        if (e + 16 <= e1) {
            int idx[16];
            #pragma unroll
            for (int q = 0; q < 4; ++q) {
                int4 t4 = *(const int4*)(tgt + e + 4 * q);
                idx[4 * q + 0] = t4.x; idx[4 * q + 1] = t4.y;
                idx[4 * q + 2] = t4.z; idx[4 * q + 3] = t4.w;
            }
            bool hit[16];
            #pragma unroll
            for (int k = 0; k < 16; ++k) hit[k] = (unsigned)(idx[k] - lo) < span;
            if (wg) {
                int od[16];
                #pragma unroll
                for (int q = 0; q < 4; ++q) {
                    int4 o4 = *(const int4*)(oth + e + 4 * q);
                    od[4 * q + 0] = o4.x; od[4 * q + 1] = o4.y;
                    od[4 * q + 2] = o4.z; od[4 * q + 3] = o4.w;
                }
                float val[16];
                #pragma unroll
                for (int k = 0; k < 16; ++k) val[k] = hit[k] ? wg[od[k]] : 0.f;
                #pragma unroll
                for (int k = 0; k < 16; ++k)
                    if (hit[k]) atomicAdd(&lds[idx[k] - lo], val[k] * scale);
            } else {
                #pragma unroll
                for (int k = 0; k < 16; ++k)
                    if (hit[k]) atomicAdd(&lds[idx[k] - lo], 1.0f);
            }
        } else {
            for (int e2 = e; e2 < e1; ++e2) {
                int t = tgt[e2];
                if ((unsigned)(t - lo) < span) {
                    float v = wg ? wg[oth[e2]] * scale : 1.0f;
                    atomicAdd(&lds[t - lo], v);
                }
            }
        }
    }
    __syncthreads();

    float* dst = rep + (((size_t)g * H + h) * B + b) * HN;
    float4* d4 = (float4*)dst;
    const float4* l4 = (const float4*)lds;
    for (int i = threadIdx.x; i < HN / 4; i += blockDim.x) d4[i] = l4[i];
}

// inv[i] = 1 / max(sum_b rep[...], 1), float4/thread, 64-thread blocks
__global__ __launch_bounds__(64) void reduce_inv(
        const float* __restrict__ rep, float* __restrict__ inv,
        int N, int HN, int H, int B) {
    int i = (blockIdx.x * 64 + threadIdx.x) * 4;
    if (i >= 2 * N) return;
    int g = (i < N) ? 0 : 1;
    int n = i - g * N;
    int h = n / HN, l = n - h * HN;
    const float* base = rep + (((size_t)g * H + h) * B) * HN + l;
    float4 s = make_float4(0.f, 0.f, 0.f, 0.f);
    #pragma unroll 16
    for (int b = 0; b < B; b++) {
        float4 v = *(const float4*)(base + (size_t)b * HN);
        s.x += v.x; s.y += v.y; s.z += v.z; s.w += v.w;
    }
    float4 r;
    r.x = 1.0f / fmaxf(s.x, 1.0f); r.y = 1.0f / fmaxf(s.y, 1.0f);
    r.z = 1.0f / fmaxf(s.z, 1.0f); r.w = 1.0f / fmaxf(s.w, 1.0f);
    *(float4*)(inv + i) = r;
}

// u = sum_b rep; optional out_u, out_w = u*inv; optional per-graph sums
__global__ __launch_bounds__(64) void reduce_u(
        const float* __restrict__ rep, const float* __restrict__ inv,
        float* __restrict__ out_u, float* __restrict__ out_w,
        float* __restrict__ sums, int s_idx, int N, int HN, int H, int B) {
    int i = (blockIdx.x * 64 + threadIdx.x) * 4;
    float tp = 0.f, ts = 0.f;
    if (i < 2 * N) {
        int g = (i < N) ? 0 : 1;
        int n = i - g * N;
        int h = n / HN, l = n - h * HN;
        const float* base = rep + (((size_t)g * H + h) * B) * HN + l;
        float4 u = make_float4(0.f, 0.f, 0.f, 0.f);
        #pragma unroll 16
        for (int b = 0; b < B; b++) {
            float4 v = *(const float4*)(base + (size_t)b * HN);
            u.x += v.x; u.y += v.y; u.z += v.z; u.w += v.w;
        }
        if (out_u) *(float4*)(out_u + i) = u;
        if (out_w) {
            float4 iv = *(const float4*)(inv + i);
            *(float4*)(out_w + i) = make_float4(u.x * iv.x, u.y * iv.y, u.z * iv.z, u.w * iv.w);
        }
        float t = u.x + u.y + u.z + u.w;
        if (g == 0) tp = t; else ts = t;
    }
    if (sums) {
        __shared__ float sm0[64], sm1[64];
        sm0[threadIdx.x] = tp; sm1[threadIdx.x] = ts;
        __syncthreads();
        for (int s = 32; s > 0; s >>= 1) {
            if ((int)threadIdx.x < s) {
                sm0[threadIdx.x] += sm0[threadIdx.x + s];
                sm1[threadIdx.x] += sm1[threadIdx.x + s];
            }
            __syncthreads();
        }
        if (threadIdx.x == 0) {
            if (sm0[0] != 0.f) atomicAdd(&sums[0 * 2 + s_idx], sm0[0]);
            if (sm1[0] != 0.f) atomicAdd(&sums[1 * 2 + s_idx], sm1[0]);
        }
    }
}

// fpart[(g*NB+blk)][c] = partial of u3^T feat over this block's rows
__global__ __launch_bounds__(256) void featsum_kernel(
        const float* __restrict__ feat_p, const float* __restrict__ feat_s,
        const float* __restrict__ u3, float* __restrict__ fpart, int N) {
    const int g = blockIdx.y;
    const float* feat = g ? feat_s : feat_p;
    const float* u = u3 + (size_t)g * N;
    const int nb = gridDim.x;
    const int col4 = threadIdx.x & 31;
    const int rgrp = threadIdx.x >> 5;
    const int rows_per_block = (N + nb - 1) / nb;
    const int r0 = blockIdx.x * rows_per_block;
    const int r1 = min(r0 + rows_per_block, N);

    const float4* f4 = (const float4*)feat;
    float4 acc = make_float4(0.f, 0.f, 0.f, 0.f);
    int n = r0 + rgrp;
    for (; n + 24 < r1; n += 32) {
        float w0 = u[n], w1 = u[n + 8], w2 = u[n + 16], w3 = u[n + 24];
        float4 v0 = f4[(size_t)n * 32 + col4];
        float4 v1 = f4[(size_t)(n + 8) * 32 + col4];
        float4 v2 = f4[(size_t)(n + 16) * 32 + col4];
        float4 v3 = f4[(size_t)(n + 24) * 32 + col4];
        acc.x += w0 * v0.x + w1 * v1.x + w2 * v2.x + w3 * v3.x;
        acc.y += w0 * v0.y + w1 * v1.y + w2 * v2.y + w3 * v3.y;
        acc.z += w0 * v0.z + w1 * v1.z + w2 * v2.z + w3 * v3.z;
        acc.w += w0 * v0.w + w1 * v1.w + w2 * v2.w + w3 * v3.w;
    }
    for (; n < r1; n += 8) {
        float wv = u[n];
        float4 v = f4[(size_t)n * 32 + col4];
        acc.x += wv * v.x; acc.y += wv * v.y; acc.z += wv * v.z; acc.w += wv * v.w;
    }
    __shared__ float4 smem[256];
    smem[threadIdx.x] = acc;
    __syncthreads();
    if (rgrp == 0) {
        float4 t = smem[col4];
        #pragma unroll
        for (int k = 1; k < 8; k++) {
            float4 o = smem[k * 32 + col4];
            t.x += o.x; t.y += o.y; t.z += o.z; t.w += o.w;
        }
        float4* dst = (float4*)(fpart + ((size_t)g * nb + blockIdx.x) * 128);
        dst[col4] = t;
    }
}

// parallel pre-reduce: fpart[2][NB][128] -> fpart2[2][16][128] (NB mult of 32)
__global__ __launch_bounds__(256) void fpart_reduce(
        const float* __restrict__ fpart, float* __restrict__ fpart2, int NB) {
    const int b = blockIdx.x, g = blockIdx.y;   // (16, 2)
    const int j = threadIdx.x & 127, half = threadIdx.x >> 7;
    const int per = NB / 16;                    // 48
    const int hp = per / 2;                     // 24
    const float* fp = fpart + ((size_t)(g * NB + b * per + half * hp)) * 128 + j;
    float s = 0.f;
    #pragma unroll 24
    for (int k = 0; k < hp; ++k) s += fp[(size_t)k * 128];
    __shared__ float sm[2][128];
    sm[half][j] = s;
    __syncthreads();
    if (half == 0) fpart2[((size_t)g * 16 + b) * 128 + j] = sm[0][j] + sm[1][j];
}

// 512 threads: split-K matvecs. j = tid&127, h = tid>>7.
__global__ __launch_bounds__(512) void final_kernel(
        const float* __restrict__ fpart2,
        const float* __restrict__ sums,
        const float* __restrict__ W0, const float* __restrict__ b0,
        const float* __restrict__ W1, const float* __restrict__ b1,
        const float* __restrict__ W2, const float* __restrict__ b2,
        const float* __restrict__ Wr, const float* __restrict__ br,
        const float* __restrict__ Wm1, const float* __restrict__ bm1,
        const float* __restrict__ Wm2, const float* __restrict__ bm2,
        float* __restrict__ out) {
    __shared__ float x[128];
    __shared__ float part[4][128];
    __shared__ float rvec[256];
    __shared__ float Avec[128], Bvec[128];
    __shared__ float gv[256];
    const int tid = threadIdx.x;
    const int j = tid & 127;
    const int h = tid >> 7;

    auto mv128 = [&](const float* __restrict__ W, float* __restrict__ buf) {
        float p = 0.f;
        const float* Wp = W + (size_t)(h * 32) * 128 + j;
        #pragma unroll
        for (int i = 0; i < 32; ++i) p += buf[h * 32 + i] * Wp[(size_t)i * 128];
        part[h][j] = p;
        __syncthreads();
        if (h == 0) buf[j] = part[0][j] + part[1][j] + part[2][j] + part[3][j];
        __syncthreads();
    };

    // 1. fpart2 reduce -> rvec
    if (tid < 256) {
        int g = tid >> 7;
        const float* fp = fpart2 + (size_t)g * 2048 + (tid & 127);
        float rv = 0.f;
        #pragma unroll
        for (int b = 0; b < 16; ++b) rv += fp[(size_t)b * 128];
        rvec[tid] = rv;
    }
    __syncthreads();

    // 2. bias chains: Avec = b0@W1@W2 (coeff s2), Bvec = b1@W2 (coeff s1)
    if (tid < 128) x[tid] = b0[tid];
    __syncthreads();
    mv128(W1, x);
    mv128(W2, x);
    if (tid < 128) Avec[tid] = x[tid];
    __syncthreads();
    if (tid < 128) x[tid] = b1[tid];
    __syncthreads();
    mv128(W2, x);
    if (tid < 128) Bvec[tid] = x[tid];
    __syncthreads();

    // 3. per-graph chain + readout sigmoid
    for (int g = 0; g < 2; ++g) {
        const float s1 = sums[g * 2 + 0];
        const float s2 = sums[g * 2 + 1];
        if (tid < 128) x[tid] = rvec[g * 128 + tid];
        __syncthreads();
        mv128(W0, x);
        mv128(W1, x);
        mv128(W2, x);
        if (tid < 128) x[tid] += s2 * Avec[tid] + s1 * Bvec[tid] + b2[tid];
        __syncthreads();
        mv128(Wr, x);
        if (tid < 128) gv[g * 128 + tid] = 1.0f / (1.0f + expf(-(x[tid] + br[tid])));
        __syncthreads();
    }

    // 4. match MLP
    {
        float p = 0.f;
        const float* Wp = Wm1 + (size_t)(h * 64) * 128 + j;
        #pragma unroll
        for (int i = 0; i < 64; ++i) p += gv[h * 64 + i] * Wp[(size_t)i * 128];
        part[h][j] = p;
        __syncthreads();
        if (h == 0)
            part[0][j] = (part[0][j] + part[1][j] + part[2][j] + part[3][j] + bm1[j]) * Wm2[j];
        __syncthreads();
        if (tid < 64) part[0][tid] += part[0][tid + 64];
        __syncthreads();
        if (tid < 32) part[0][tid] += part[0][tid + 32];
        __syncthreads();
        if (tid < 16) part[0][tid] += part[0][tid + 16];
        __syncthreads();
        if (tid < 8) part[0][tid] += part[0][tid + 8];
        __syncthreads();
        if (tid < 4) part[0][tid] += part[0][tid + 4];
        __syncthreads();
        if (tid < 2) part[0][tid] += part[0][tid + 2];
        __syncthreads();
        if (tid == 0) out[0] = 1.0f / (1.0f + expf(-(part[0][0] + part[0][1] + bm2[0])));
    }
}

extern "C" void kernel_launch(void* const* d_in, const int* in_sizes, int n_in,
                              void* d_out, int out_size, void* d_ws, size_t ws_size,
                              hipStream_t stream) {
    const float* feat_p = (const float*)d_in[0];
    const int*   src_p  = (const int*)d_in[1];
    const int*   dst_p  = (const int*)d_in[2];
    const float* feat_s = (const float*)d_in[3];
    const int*   src_s  = (const int*)d_in[4];
    const int*   dst_s  = (const int*)d_in[5];
    const float* W0 = (const float*)d_in[6];
    const float* b0 = (const float*)d_in[7];
    const float* W1 = (const float*)d_in[8];
    const float* b1 = (const float*)d_in[9];
    const float* W2 = (const float*)d_in[10];
    const float* b2 = (const float*)d_in[11];
    const float* Wr = (const float*)d_in[12];
    const float* br = (const float*)d_in[13];
    const float* Wm1 = (const float*)d_in[14];
    const float* bm1 = (const float*)d_in[15];
    const float* Wm2 = (const float*)d_in[16];
    const float* bm2 = (const float*)d_in[17];
    float* out = (float*)d_out;

    const int N = in_sizes[0] / D;   // 50000
    const int E = in_sizes[1];       // 1600000
    const int N2 = 2 * N;

    const int H = 4;
    int HN = (N + H - 1) / H;
    HN = (HN + 3) & ~3;              // 12500
    const int NB = 768;              // featsum blocks per graph (mult of 32)

    // ws (floats): sums[4]|pad16 | inv[2N]|w1[2N]|w2[2N]|u3[2N] |
    //              fpart[2*NB*128] | fpart2[2*16*128] | rep[2*H*B*HN]
    const size_t head = 16 + 4 * (size_t)N2 + (size_t)2 * NB * 128 + 2 * 16 * 128;
    size_t avail = ws_size / sizeof(float);
    int B = 8;
    if (avail > head) {
        size_t bmax = (avail - head) / ((size_t)2 * H * HN);
        if (bmax > 96) bmax = 96;
        B = (int)(bmax & ~(size_t)7);
        if (B < 1) B = 1;
    } else {
        B = 1;
    }

    float* ws     = (float*)d_ws;
    float* sums   = ws;
    float* inv    = ws + 16;
    float* w1     = inv + N2;
    float* w2     = w1 + N2;
    float* u3     = w2 + N2;
    float* fpart  = u3 + N2;
    float* fpart2 = fpart + (size_t)2 * NB * 128;
    float* rep    = fpart2 + 2 * 16 * 128;

    hipMemsetAsync(d_ws, 0, 16 * sizeof(float), stream);  // sums only

    const int BTS = 512;             // scan block (8 waves, 50KB LDS, 3/CU)
    const int BT = 256;
    const dim3 sgrid(B, H, 2);
    const size_t lds_bytes = (size_t)HN * sizeof(float);
    const int gQ = (N2 / 4 + 63) / 64;
    const float u0 = 1.0f / (float)N;

    scan_scatter<<<sgrid, BTS, lds_bytes, stream>>>(dst_p, nullptr, dst_s, nullptr,
                                                    nullptr, rep, E, N, HN, B, H, 1.0f);
    reduce_inv<<<gQ, 64, 0, stream>>>(rep, inv, N, HN, H, B);

    scan_scatter<<<sgrid, BTS, lds_bytes, stream>>>(src_p, dst_p, src_s, dst_s,
                                                    inv, rep, E, N, HN, B, H, u0);
    reduce_u<<<gQ, 64, 0, stream>>>(rep, inv, nullptr, w1, sums, 0, N, HN, H, B);

    scan_scatter<<<sgrid, BTS, lds_bytes, stream>>>(src_p, dst_p, src_s, dst_s,
                                                    w1, rep, E, N, HN, B, H, 1.0f);
    reduce_u<<<gQ, 64, 0, stream>>>(rep, inv, nullptr, w2, sums, 1, N, HN, H, B);

    scan_scatter<<<sgrid, BTS, lds_bytes, stream>>>(src_p, dst_p, src_s, dst_s,
                                                    w2, rep, E, N, HN, B, H, 1.0f);
    reduce_u<<<gQ, 64, 0, stream>>>(rep, inv, u3, nullptr, nullptr, 0, N, HN, H, B);

    featsum_kernel<<<dim3(NB, 2), BT, 0, stream>>>(feat_p, feat_s, u3, fpart, N);
    fpart_reduce<<<dim3(16, 2), BT, 0, stream>>>(fpart, fpart2, NB);

    final_kernel<<<1, 512, 0, stream>>>(fpart2, sums, W0, b0, W1, b1, W2, b2,
                                        Wr, br, Wm1, bm1, Wm2, bm2, out);
}

// Round 9
// 288.763 us; speedup vs baseline: 1.2155x; 1.0507x over previous
//
#include <hip/hip_runtime.h>
#include <math.h>

#define D 128

// ---------------------------------------------------------------------------
// Collapsed linear GCN (math unchanged, absmax 0.0 since R0):
//   u0 = 1/N,  u_{k+1}[s] = sum_{e: src_e=s} inv_deg[dst_e] * u_k[dst_e]
//   mean(h3) = r@W0W1W2 + s2*(b0@W1W2) + s1*(b1@W2) + b2,  r = u3^T feat
// R2-R7: LDS histograms, 16-wide ILP, 512-thread scans, split-K final.
// R8: reduces were 25K threads @ 96 strided loads (latency-bound) ->
// 256-thread blocks, 64 quads x 4 B-slices + LDS combine. featsum u-loads
// vectorized (float4 per 4 rows). memset launch folded into deg scan.
// ---------------------------------------------------------------------------

// scatter pass: rep[g][h][b][HN] partial sums.
//   deg pass:  tgt = dst arrays, w = null  -> +1 per edge (also zeroes sums)
//   prop pass: tgt = src arrays, oth = dst, w -> + w[g*N + dst[e]] * scale
__global__ __launch_bounds__(512) void scan_scatter(
        const int* __restrict__ tgt_p, const int* __restrict__ oth_p,
        const int* __restrict__ tgt_s, const int* __restrict__ oth_s,
        const float* __restrict__ w, float* __restrict__ rep,
        float* __restrict__ sums,
        int E, int N, int HN, int B, int H, float scale) {
    const int b = blockIdx.x, h = blockIdx.y, g = blockIdx.z;
    const int* tgt = g ? tgt_s : tgt_p;
    const int* oth = g ? oth_s : oth_p;
    const float* wg = w ? (w + (size_t)g * N) : nullptr;

    if (!w && b == 0 && h == 0 && g == 0 && threadIdx.x < 16) sums[threadIdx.x] = 0.f;

    extern __shared__ float lds[];  // HN floats (HN % 4 == 0)
    {
        float4 z = make_float4(0.f, 0.f, 0.f, 0.f);
        float4* l4 = (float4*)lds;
        for (int i = threadIdx.x; i < HN / 4; i += blockDim.x) l4[i] = z;
    }
    __syncthreads();

    const int lo = h * HN;
    const int hi = min(lo + HN, N);
    const unsigned span = (unsigned)(hi - lo);
    int C = (E + B - 1) / B;
    C = (C + 15) & ~15;
    const int e0 = b * C;
    const int e1 = min(e0 + C, E);

    for (int e = e0 + (int)threadIdx.x * 16; e < e1; e += (int)blockDim.x * 16) {
        if (e + 16 <= e1) {
            int idx[16];
            #pragma unroll
            for (int q = 0; q < 4; ++q) {
                int4 t4 = *(const int4*)(tgt + e + 4 * q);
                idx[4 * q + 0] = t4.x; idx[4 * q + 1] = t4.y;
                idx[4 * q + 2] = t4.z; idx[4 * q + 3] = t4.w;
            }
            bool hit[16];
            #pragma unroll
            for (int k = 0; k < 16; ++k) hit[k] = (unsigned)(idx[k] - lo) < span;
            if (wg) {
                int od[16];
                #pragma unroll
                for (int q = 0; q < 4; ++q) {
                    int4 o4 = *(const int4*)(oth + e + 4 * q);
                    od[4 * q + 0] = o4.x; od[4 * q + 1] = o4.y;
                    od[4 * q + 2] = o4.z; od[4 * q + 3] = o4.w;
                }
                float val[16];
                #pragma unroll
                for (int k = 0; k < 16; ++k) val[k] = hit[k] ? wg[od[k]] : 0.f;
                #pragma unroll
                for (int k = 0; k < 16; ++k)
                    if (hit[k]) atomicAdd(&lds[idx[k] - lo], val[k] * scale);
            } else {
                #pragma unroll
                for (int k = 0; k < 16; ++k)
                    if (hit[k]) atomicAdd(&lds[idx[k] - lo], 1.0f);
            }
        } else {
            for (int e2 = e; e2 < e1; ++e2) {
                int t = tgt[e2];
                if ((unsigned)(t - lo) < span) {
                    float v = wg ? wg[oth[e2]] * scale : 1.0f;
                    atomicAdd(&lds[t - lo], v);
                }
            }
        }
    }
    __syncthreads();

    float* dst = rep + (((size_t)g * H + h) * B + b) * HN;
    float4* d4 = (float4*)dst;
    const float4* l4 = (const float4*)lds;
    for (int i = threadIdx.x; i < HN / 4; i += blockDim.x) d4[i] = l4[i];
}

// 256 threads = 64 quads x 4 B-slices; each thread sums B/4 partials.
// inv[i] = 1 / max(deg, 1)
__global__ __launch_bounds__(256) void reduce_inv(
        const float* __restrict__ rep, float* __restrict__ inv,
        int N, int HN, int H, int B) {
    const int lane = threadIdx.x & 63;
    const int s = threadIdx.x >> 6;
    const int i = (blockIdx.x * 64 + lane) * 4;
    const int bps = B >> 2;
    float4 u = make_float4(0.f, 0.f, 0.f, 0.f);
    if (i < 2 * N) {
        int g = (i < N) ? 0 : 1;
        int n = i - g * N;
        int h = n / HN, l = n - h * HN;
        const float* base = rep + (((size_t)g * H + h) * B + (size_t)s * bps) * HN + l;
        #pragma unroll 24
        for (int b = 0; b < bps; b++) {
            float4 v = *(const float4*)(base + (size_t)b * HN);
            u.x += v.x; u.y += v.y; u.z += v.z; u.w += v.w;
        }
    }
    __shared__ float4 sm[256];
    sm[threadIdx.x] = u;
    __syncthreads();
    if (s == 0 && i < 2 * N) {
        float4 a = sm[lane], b4 = sm[64 + lane], c = sm[128 + lane], d = sm[192 + lane];
        float4 r;
        r.x = 1.0f / fmaxf(a.x + b4.x + c.x + d.x, 1.0f);
        r.y = 1.0f / fmaxf(a.y + b4.y + c.y + d.y, 1.0f);
        r.z = 1.0f / fmaxf(a.z + b4.z + c.z + d.z, 1.0f);
        r.w = 1.0f / fmaxf(a.w + b4.w + c.w + d.w, 1.0f);
        *(float4*)(inv + i) = r;
    }
}

// u = sum_b rep; optional out_u, out_w = u*inv; optional per-graph sums
__global__ __launch_bounds__(256) void reduce_u(
        const float* __restrict__ rep, const float* __restrict__ inv,
        float* __restrict__ out_u, float* __restrict__ out_w,
        float* __restrict__ sums, int s_idx, int N, int HN, int H, int B) {
    const int lane = threadIdx.x & 63;
    const int s = threadIdx.x >> 6;
    const int i = (blockIdx.x * 64 + lane) * 4;
    const int bps = B >> 2;
    float4 u = make_float4(0.f, 0.f, 0.f, 0.f);
    if (i < 2 * N) {
        int g = (i < N) ? 0 : 1;
        int n = i - g * N;
        int h = n / HN, l = n - h * HN;
        const float* base = rep + (((size_t)g * H + h) * B + (size_t)s * bps) * HN + l;
        #pragma unroll 24
        for (int b = 0; b < bps; b++) {
            float4 v = *(const float4*)(base + (size_t)b * HN);
            u.x += v.x; u.y += v.y; u.z += v.z; u.w += v.w;
        }
    }
    __shared__ float4 sm[256];
    __shared__ float s0[64], s1[64];
    sm[threadIdx.x] = u;
    __syncthreads();
    if (s == 0) {
        float tp = 0.f, ts = 0.f;
        if (i < 2 * N) {
            float4 a = sm[lane], b4 = sm[64 + lane], c = sm[128 + lane], d = sm[192 + lane];
            float4 uu;
            uu.x = a.x + b4.x + c.x + d.x;
            uu.y = a.y + b4.y + c.y + d.y;
            uu.z = a.z + b4.z + c.z + d.z;
            uu.w = a.w + b4.w + c.w + d.w;
            if (out_u) *(float4*)(out_u + i) = uu;
            if (out_w) {
                float4 iv = *(const float4*)(inv + i);
                *(float4*)(out_w + i) =
                    make_float4(uu.x * iv.x, uu.y * iv.y, uu.z * iv.z, uu.w * iv.w);
            }
            float t = uu.x + uu.y + uu.z + uu.w;
            if (i < N) tp = t; else ts = t;
        }
        s0[lane] = tp; s1[lane] = ts;
    }
    __syncthreads();
    if (sums) {
        for (int st = 32; st > 0; st >>= 1) {
            if ((int)threadIdx.x < st) {
                s0[threadIdx.x] += s0[threadIdx.x + st];
                s1[threadIdx.x] += s1[threadIdx.x + st];
            }
            __syncthreads();
        }
        if (threadIdx.x == 0) {
            if (s0[0] != 0.f) atomicAdd(&sums[0 * 2 + s_idx], s0[0]);
            if (s1[0] != 0.f) atomicAdd(&sums[1 * 2 + s_idx], s1[0]);
        }
    }
}

// fpart[(g*NB+blk)][c] = partial of u3^T feat over this block's rows.
// rpb multiple of 4; u loaded as float4 per 4-row quad.
__global__ __launch_bounds__(256) void featsum_kernel(
        const float* __restrict__ feat_p, const float* __restrict__ feat_s,
        const float* __restrict__ u3, float* __restrict__ fpart, int N, int rpb) {
    const int g = blockIdx.y;
    const float* feat = g ? feat_s : feat_p;
    const float* u = u3 + (size_t)g * N;
    const int nb = gridDim.x;
    const int col4 = threadIdx.x & 31;
    const int rgrp = threadIdx.x >> 5;   // 0..7
    const int r0 = blockIdx.x * rpb;
    const int r1 = min(r0 + rpb, N);

    const float4* f4 = (const float4*)feat;
    float4 acc = make_float4(0.f, 0.f, 0.f, 0.f);
    for (int n = r0 + rgrp * 4; n + 3 < r1; n += 32) {
        float4 uu = *(const float4*)(u + n);
        float4 v0 = f4[(size_t)n * 32 + col4];
        float4 v1 = f4[(size_t)(n + 1) * 32 + col4];
        float4 v2 = f4[(size_t)(n + 2) * 32 + col4];
        float4 v3 = f4[(size_t)(n + 3) * 32 + col4];
        acc.x += uu.x * v0.x + uu.y * v1.x + uu.z * v2.x + uu.w * v3.x;
        acc.y += uu.x * v0.y + uu.y * v1.y + uu.z * v2.y + uu.w * v3.y;
        acc.z += uu.x * v0.z + uu.y * v1.z + uu.z * v2.z + uu.w * v3.z;
        acc.w += uu.x * v0.w + uu.y * v1.w + uu.z * v2.w + uu.w * v3.w;
    }
    __shared__ float4 smem[256];
    smem[threadIdx.x] = acc;
    __syncthreads();
    if (rgrp == 0) {
        float4 t = smem[col4];
        #pragma unroll
        for (int k = 1; k < 8; k++) {
            float4 o = smem[k * 32 + col4];
            t.x += o.x; t.y += o.y; t.z += o.z; t.w += o.w;
        }
        float4* dst = (float4*)(fpart + ((size_t)g * nb + blockIdx.x) * 128);
        dst[col4] = t;
    }
}

// parallel pre-reduce: fpart[2][NB][128] -> fpart2[2][16][128] (NB mult of 32)
__global__ __launch_bounds__(256) void fpart_reduce(
        const float* __restrict__ fpart, float* __restrict__ fpart2, int NB) {
    const int b = blockIdx.x, g = blockIdx.y;   // (16, 2)
    const int j = threadIdx.x & 127, half = threadIdx.x >> 7;
    const int per = NB / 16;
    const int hp = per / 2;
    const float* fp = fpart + ((size_t)(g * NB + b * per + half * hp)) * 128 + j;
    float s = 0.f;
    #pragma unroll 24
    for (int k = 0; k < hp; ++k) s += fp[(size_t)k * 128];
    __shared__ float sm[2][128];
    sm[half][j] = s;
    __syncthreads();
    if (half == 0) fpart2[((size_t)g * 16 + b) * 128 + j] = sm[0][j] + sm[1][j];
}

// 512 threads: split-K matvecs. j = tid&127, h = tid>>7.
__global__ __launch_bounds__(512) void final_kernel(
        const float* __restrict__ fpart2,
        const float* __restrict__ sums,
        const float* __restrict__ W0, const float* __restrict__ b0,
        const float* __restrict__ W1, const float* __restrict__ b1,
        const float* __restrict__ W2, const float* __restrict__ b2,
        const float* __restrict__ Wr, const float* __restrict__ br,
        const float* __restrict__ Wm1, const float* __restrict__ bm1,
        const float* __restrict__ Wm2, const float* __restrict__ bm2,
        float* __restrict__ out) {
    __shared__ float x[128];
    __shared__ float part[4][128];
    __shared__ float rvec[256];
    __shared__ float Avec[128], Bvec[128];
    __shared__ float gv[256];
    const int tid = threadIdx.x;
    const int j = tid & 127;
    const int h = tid >> 7;

    auto mv128 = [&](const float* __restrict__ W, float* __restrict__ buf) {
        float p = 0.f;
        const float* Wp = W + (size_t)(h * 32) * 128 + j;
        #pragma unroll
        for (int i = 0; i < 32; ++i) p += buf[h * 32 + i] * Wp[(size_t)i * 128];
        part[h][j] = p;
        __syncthreads();
        if (h == 0) buf[j] = part[0][j] + part[1][j] + part[2][j] + part[3][j];
        __syncthreads();
    };

    if (tid < 256) {
        int g = tid >> 7;
        const float* fp = fpart2 + (size_t)g * 2048 + (tid & 127);
        float rv = 0.f;
        #pragma unroll
        for (int b = 0; b < 16; ++b) rv += fp[(size_t)b * 128];
        rvec[tid] = rv;
    }
    __syncthreads();

    if (tid < 128) x[tid] = b0[tid];
    __syncthreads();
    mv128(W1, x);
    mv128(W2, x);
    if (tid < 128) Avec[tid] = x[tid];
    __syncthreads();
    if (tid < 128) x[tid] = b1[tid];
    __syncthreads();
    mv128(W2, x);
    if (tid < 128) Bvec[tid] = x[tid];
    __syncthreads();

    for (int g = 0; g < 2; ++g) {
        const float s1 = sums[g * 2 + 0];
        const float s2 = sums[g * 2 + 1];
        if (tid < 128) x[tid] = rvec[g * 128 + tid];
        __syncthreads();
        mv128(W0, x);
        mv128(W1, x);
        mv128(W2, x);
        if (tid < 128) x[tid] += s2 * Avec[tid] + s1 * Bvec[tid] + b2[tid];
        __syncthreads();
        mv128(Wr, x);
        if (tid < 128) gv[g * 128 + tid] = 1.0f / (1.0f + expf(-(x[tid] + br[tid])));
        __syncthreads();
    }

    {
        float p = 0.f;
        const float* Wp = Wm1 + (size_t)(h * 64) * 128 + j;
        #pragma unroll
        for (int i = 0; i < 64; ++i) p += gv[h * 64 + i] * Wp[(size_t)i * 128];
        part[h][j] = p;
        __syncthreads();
        if (h == 0)
            part[0][j] = (part[0][j] + part[1][j] + part[2][j] + part[3][j] + bm1[j]) * Wm2[j];
        __syncthreads();
        if (tid < 64) part[0][tid] += part[0][tid + 64];
        __syncthreads();
        if (tid < 32) part[0][tid] += part[0][tid + 32];
        __syncthreads();
        if (tid < 16) part[0][tid] += part[0][tid + 16];
        __syncthreads();
        if (tid < 8) part[0][tid] += part[0][tid + 8];
        __syncthreads();
        if (tid < 4) part[0][tid] += part[0][tid + 4];
        __syncthreads();
        if (tid < 2) part[0][tid] += part[0][tid + 2];
        __syncthreads();
        if (tid == 0) out[0] = 1.0f / (1.0f + expf(-(part[0][0] + part[0][1] + bm2[0])));
    }
}

extern "C" void kernel_launch(void* const* d_in, const int* in_sizes, int n_in,
                              void* d_out, int out_size, void* d_ws, size_t ws_size,
                              hipStream_t stream) {
    const float* feat_p = (const float*)d_in[0];
    const int*   src_p  = (const int*)d_in[1];
    const int*   dst_p  = (const int*)d_in[2];
    const float* feat_s = (const float*)d_in[3];
    const int*   src_s  = (const int*)d_in[4];
    const int*   dst_s  = (const int*)d_in[5];
    const float* W0 = (const float*)d_in[6];
    const float* b0 = (const float*)d_in[7];
    const float* W1 = (const float*)d_in[8];
    const float* b1 = (const float*)d_in[9];
    const float* W2 = (const float*)d_in[10];
    const float* b2 = (const float*)d_in[11];
    const float* Wr = (const float*)d_in[12];
    const float* br = (const float*)d_in[13];
    const float* Wm1 = (const float*)d_in[14];
    const float* bm1 = (const float*)d_in[15];
    const float* Wm2 = (const float*)d_in[16];
    const float* bm2 = (const float*)d_in[17];
    float* out = (float*)d_out;

    const int N = in_sizes[0] / D;   // 50000
    const int E = in_sizes[1];       // 1600000
    const int N2 = 2 * N;

    const int H = 4;
    int HN = (N + H - 1) / H;
    HN = (HN + 3) & ~3;              // 12500
    const int NB = 768;              // featsum blocks per graph (mult of 32)
    int rpb = ((N + NB - 1) / NB + 3) & ~3;   // rows per featsum block, mult of 4

    // ws (floats): sums[4]|pad16 | inv[2N]|w1[2N]|w2[2N]|u3[2N] |
    //              fpart[2*NB*128] | fpart2[2*16*128] | rep[2*H*B*HN]
    const size_t head = 16 + 4 * (size_t)N2 + (size_t)2 * NB * 128 + 2 * 16 * 128;
    size_t avail = ws_size / sizeof(float);
    int B = 8;
    if (avail > head) {
        size_t bmax = (avail - head) / ((size_t)2 * H * HN);
        if (bmax > 96) bmax = 96;
        B = (int)(bmax & ~(size_t)7);
        if (B < 8) B = 8;
    }

    float* ws     = (float*)d_ws;
    float* sums   = ws;
    float* inv    = ws + 16;
    float* w1     = inv + N2;
    float* w2     = w1 + N2;
    float* u3     = w2 + N2;
    float* fpart  = u3 + N2;
    float* fpart2 = fpart + (size_t)2 * NB * 128;
    float* rep    = fpart2 + 2 * 16 * 128;

    const int BTS = 512;             // scan block (8 waves, 50KB LDS, 3/CU)
    const int BT = 256;
    const dim3 sgrid(B, H, 2);
    const size_t lds_bytes = (size_t)HN * sizeof(float);
    const int gQ = (N2 / 4 + 63) / 64;   // 64 quads per reduce block
    const float u0 = 1.0f / (float)N;

    scan_scatter<<<sgrid, BTS, lds_bytes, stream>>>(dst_p, nullptr, dst_s, nullptr,
                                                    nullptr, rep, sums, E, N, HN, B, H, 1.0f);
    reduce_inv<<<gQ, BT, 0, stream>>>(rep, inv, N, HN, H, B);

    scan_scatter<<<sgrid, BTS, lds_bytes, stream>>>(src_p, dst_p, src_s, dst_s,
                                                    inv, rep, sums, E, N, HN, B, H, u0);
    reduce_u<<<gQ, BT, 0, stream>>>(rep, inv, nullptr, w1, sums, 0, N, HN, H, B);

    scan_scatter<<<sgrid, BTS, lds_bytes, stream>>>(src_p, dst_p, src_s, dst_s,
                                                    w1, rep, sums, E, N, HN, B, H, 1.0f);
    reduce_u<<<gQ, BT, 0, stream>>>(rep, inv, nullptr, w2, sums, 1, N, HN, H, B);

    scan_scatter<<<sgrid, BTS, lds_bytes, stream>>>(src_p, dst_p, src_s, dst_s,
                                                    w2, rep, sums, E, N, HN, B, H, 1.0f);
    reduce_u<<<gQ, BT, 0, stream>>>(rep, inv, u3, nullptr, nullptr, 0, N, HN, H, B);

    featsum_kernel<<<dim3(NB, 2), BT, 0, stream>>>(feat_p, feat_s, u3, fpart, N, rpb);
    fpart_reduce<<<dim3(16, 2), BT, 0, stream>>>(fpart, fpart2, NB);

    final_kernel<<<1, 512, 0, stream>>>(fpart2, sums, W0, b0, W1, b1, W2, b2,
                                        Wr, br, Wm1, bm1, Wm2, bm2, out);
}